// Round 1
// baseline (599.018 us; speedup 1.0000x reference)
//
#include <hip/hip_runtime.h>
#include <math.h>

// SkipGram negative-sampling loss on MI355X.
// inputs: d_in[0]=u_weight [100000,300] f32, d_in[1]=v_weight [100000,300] f32,
//         d_in[2]=pos_u [65536] i32, d_in[3]=pos_v [65536] i32, d_in[4]=neg_v [65536,10] i32
// output: d_out[0] = mean_b( softplus(-clip(u.v)) + sum_k softplus(clip(u.negk)) )

#define VOCAB 100000
#define DIM   300
#define B_TOT 65536
#define K_NEG 10

constexpr int BLOCKS = 2048;
constexpr int TPB    = 256;
constexpr int WAVES  = BLOCKS * (TPB / 64);   // 8192
constexpr int B_PER_WAVE = B_TOT / WAVES;     // 8

__device__ __forceinline__ float dot4(float4 a, float4 b) {
    return a.x * b.x + a.y * b.y + a.z * b.z + a.w * b.w;
}

// row = 300 floats = 75 float4 (1200 B, 16B-aligned since 1200 % 16 == 0).
// lane i reads chunk i; lanes 0..10 also read chunk 64+i.
__global__ __launch_bounds__(TPB, 8) void sg_main(
    const float* __restrict__ uw, const float* __restrict__ vw,
    const int* __restrict__ pos_u, const int* __restrict__ pos_v,
    const int* __restrict__ neg_v, float* __restrict__ block_sums)
{
    const int lane = threadIdx.x & 63;
    const int wave_in_block = threadIdx.x >> 6;
    const int gwave = blockIdx.x * (TPB / 64) + wave_in_block;
    const bool c1ok = lane < 11;
    const float4 zero4 = make_float4(0.f, 0.f, 0.f, 0.f);

    float acc = 0.f;

    for (int i = 0; i < B_PER_WAVE; ++i) {
        const int b = gwave * B_PER_WAVE + i;

        const int iu = pos_u[b];
        const float4* ur = (const float4*)(uw + (size_t)iu * DIM);
        float4 u0 = ur[lane];
        float4 u1 = c1ok ? ur[64 + lane] : zero4;

        float part[K_NEG + 1];
        {
            const int iv = pos_v[b];
            const float4* vr = (const float4*)(vw + (size_t)iv * DIM);
            float4 v0 = vr[lane];
            float4 v1 = c1ok ? vr[64 + lane] : zero4;
            part[0] = dot4(u0, v0) + dot4(u1, v1);
        }
        #pragma unroll
        for (int k = 0; k < K_NEG; ++k) {
            const int in = neg_v[b * K_NEG + k];
            const float4* nr = (const float4*)(vw + (size_t)in * DIM);
            float4 n0 = nr[lane];
            float4 n1 = c1ok ? nr[64 + lane] : zero4;
            part[k + 1] = dot4(u0, n0) + dot4(u1, n1);
        }

        // Butterfly-reduce all 11 partials across the 64-lane wave.
        // After this every lane holds the full dot products (broadcast).
        #pragma unroll
        for (int s = 1; s < 64; s <<= 1) {
            #pragma unroll
            for (int j = 0; j < K_NEG + 1; ++j)
                part[j] += __shfl_xor(part[j], s, 64);
        }

        // pos: -log_sigmoid(score) = softplus(-score); neg: softplus(neg_score)
        float score = fminf(fmaxf(part[0], -10.f), 10.f);
        float loss = __logf(1.f + __expf(-score));
        #pragma unroll
        for (int k = 0; k < K_NEG; ++k) {
            float ns = fminf(fmaxf(part[k + 1], -10.f), 10.f);
            loss += __logf(1.f + __expf(ns));
        }
        acc += loss;   // uniform across lanes
    }

    __shared__ float red[TPB / 64];
    if (lane == 0) red[wave_in_block] = acc;
    __syncthreads();
    if (threadIdx.x == 0)
        block_sums[blockIdx.x] = red[0] + red[1] + red[2] + red[3];
}

__global__ __launch_bounds__(256) void sg_finalize(
    const float* __restrict__ bs, float* __restrict__ out)
{
    float s = 0.f;
    for (int i = threadIdx.x; i < BLOCKS; i += 256) s += bs[i];
    #pragma unroll
    for (int off = 1; off < 64; off <<= 1) s += __shfl_xor(s, off, 64);
    __shared__ float red[4];
    const int wave = threadIdx.x >> 6;
    if ((threadIdx.x & 63) == 0) red[wave] = s;
    __syncthreads();
    if (threadIdx.x == 0)
        out[0] = (red[0] + red[1] + red[2] + red[3]) * (1.0f / (float)B_TOT);
}

extern "C" void kernel_launch(void* const* d_in, const int* in_sizes, int n_in,
                              void* d_out, int out_size, void* d_ws, size_t ws_size,
                              hipStream_t stream) {
    const float* uw    = (const float*)d_in[0];
    const float* vw    = (const float*)d_in[1];
    const int*   pos_u = (const int*)d_in[2];
    const int*   pos_v = (const int*)d_in[3];
    const int*   neg_v = (const int*)d_in[4];
    float* out = (float*)d_out;
    float* block_sums = (float*)d_ws;   // BLOCKS floats, written (not accumulated) every call

    sg_main<<<BLOCKS, TPB, 0, stream>>>(uw, vw, pos_u, pos_v, neg_v, block_sums);
    sg_finalize<<<1, 256, 0, stream>>>(block_sums, out);
}

// Round 2
// 364.524 us; speedup vs baseline: 1.6433x; 1.6433x over previous
//
#include <hip/hip_runtime.h>
#include <math.h>

// SkipGram negative-sampling loss on MI355X — round 2: MLP-oriented rewrite.
// Per b: gather u-row + pos_v-row + 10 neg-rows (12 rows x 1200 B), 11 dots,
// clip, softplus, mean. Latency-bound random gather -> issue ALL 24 row-chunk
// loads per b before any compute (scalar base addresses, lane*16 offsets).

#define DIM   300
#define B_TOT 65536
#define K_NEG 10
#define NROW  (K_NEG + 2)   // u, pos_v, 10 negs

constexpr int BLOCKS = 2048;
constexpr int TPB    = 256;
constexpr int WAVES  = BLOCKS * (TPB / 64);   // 8192
constexpr int B_PER_WAVE = B_TOT / WAVES;     // 8

__device__ __forceinline__ float dot4(float4 a, float4 b) {
    return a.x * b.x + a.y * b.y + a.z * b.z + a.w * b.w;
}

// Row = 75 float4. Lane i covers chunk i (lanes 0..63); lanes 0..10 also
// cover chunks 64..74.
__global__ __launch_bounds__(TPB, 4) void sg_main(
    const float* __restrict__ uw, const float* __restrict__ vw,
    const int* __restrict__ pos_u, const int* __restrict__ pos_v,
    const int* __restrict__ neg_v, float* __restrict__ block_sums)
{
    const int lane = threadIdx.x & 63;
    const int wib  = threadIdx.x >> 6;
    int gw = blockIdx.x * (TPB / 64) + wib;
    gw = __builtin_amdgcn_readfirstlane(gw);     // wave-uniform -> scalar

    const bool c1ok = lane < (75 - 64);          // lanes 0..10

    float acc = 0.f;

    #pragma unroll 1
    for (int i = 0; i < B_PER_WAVE; ++i) {
        const int b = gw * B_PER_WAVE + i;       // scalar

        // --- scalar index loads (s_load) ---
        const int iu = pos_u[b];
        const int iv = pos_v[b];
        int nx[K_NEG];
        #pragma unroll
        for (int k = 0; k < K_NEG; ++k) nx[k] = neg_v[b * K_NEG + k];

        // --- scalar row base pointers ---
        const float4* pr[NROW];
        pr[0] = (const float4*)(uw + (size_t)iu * DIM);
        pr[1] = (const float4*)(vw + (size_t)iv * DIM);
        #pragma unroll
        for (int k = 0; k < K_NEG; ++k)
            pr[2 + k] = (const float4*)(vw + (size_t)nx[k] * DIM);

        // --- issue ALL loads before any compute: 12x chunk0 + 12x chunk1 ---
        float4 c0[NROW];
        #pragma unroll
        for (int j = 0; j < NROW; ++j) c0[j] = pr[j][lane];

        float4 c1[NROW];
        if (c1ok) {
            #pragma unroll
            for (int j = 0; j < NROW; ++j) c1[j] = pr[j][64 + lane];
        }

        // --- per-lane partial dots (c1 garbage on masked lanes is selected away) ---
        float part[K_NEG + 1];
        #pragma unroll
        for (int j = 1; j < NROW; ++j) {
            float p = dot4(c0[j], c0[0]);
            float q = dot4(c1[j], c1[0]);
            part[j - 1] = p + (c1ok ? q : 0.f);
        }

        // --- butterfly reduce all 11 dots across the wave (broadcast result) ---
        #pragma unroll
        for (int s = 1; s < 64; s <<= 1) {
            #pragma unroll
            for (int j = 0; j < K_NEG + 1; ++j)
                part[j] += __shfl_xor(part[j], s, 64);
        }

        // pos: softplus(-score); neg: softplus(+score)
        float score = fminf(fmaxf(part[0], -10.f), 10.f);
        float loss = __logf(1.f + __expf(-score));
        #pragma unroll
        for (int k = 0; k < K_NEG; ++k) {
            float ns = fminf(fmaxf(part[k + 1], -10.f), 10.f);
            loss += __logf(1.f + __expf(ns));
        }
        acc += loss;   // uniform across lanes
    }

    __shared__ float red[TPB / 64];
    if (lane == 0) red[wib] = acc;
    __syncthreads();
    if (threadIdx.x == 0)
        block_sums[blockIdx.x] = red[0] + red[1] + red[2] + red[3];
}

__global__ __launch_bounds__(256) void sg_finalize(
    const float* __restrict__ bs, float* __restrict__ out)
{
    float s = 0.f;
    for (int i = threadIdx.x; i < BLOCKS; i += 256) s += bs[i];
    #pragma unroll
    for (int off = 1; off < 64; off <<= 1) s += __shfl_xor(s, off, 64);
    __shared__ float red[4];
    const int wave = threadIdx.x >> 6;
    if ((threadIdx.x & 63) == 0) red[wave] = s;
    __syncthreads();
    if (threadIdx.x == 0)
        out[0] = (red[0] + red[1] + red[2] + red[3]) * (1.0f / (float)B_TOT);
}

extern "C" void kernel_launch(void* const* d_in, const int* in_sizes, int n_in,
                              void* d_out, int out_size, void* d_ws, size_t ws_size,
                              hipStream_t stream) {
    const float* uw    = (const float*)d_in[0];
    const float* vw    = (const float*)d_in[1];
    const int*   pos_u = (const int*)d_in[2];
    const int*   pos_v = (const int*)d_in[3];
    const int*   neg_v = (const int*)d_in[4];
    float* out = (float*)d_out;
    float* block_sums = (float*)d_ws;

    sg_main<<<BLOCKS, TPB, 0, stream>>>(uw, vw, pos_u, pos_v, neg_v, block_sums);
    sg_finalize<<<1, 256, 0, stream>>>(block_sums, out);
}

// Round 4
// 335.171 us; speedup vs baseline: 1.7872x; 1.0876x over previous
//
#include <hip/hip_runtime.h>
#include <math.h>

// SkipGram negative-sampling loss on MI355X — round 3b (fix nt-load type).
//  (1) chunk-1 loads unconditional with in-bounds fallback chunk index
//      (R2's divergent c1[] array was demoted to scratch: 53 MB spill writes).
//  (2) u-row loads non-temporal via clang ext_vector_type (HIP float4 is a
//      struct — __builtin_nontemporal_load rejects it).

#define DIM   300
#define B_TOT 65536
#define K_NEG 10
#define NROW  (K_NEG + 2)   // u, pos_v, 10 negs

constexpr int BLOCKS = 2048;
constexpr int TPB    = 256;
constexpr int WAVES  = BLOCKS * (TPB / 64);   // 8192
constexpr int B_PER_WAVE = B_TOT / WAVES;     // 8

typedef float vf4 __attribute__((ext_vector_type(4)));

__device__ __forceinline__ float dot4(vf4 a, vf4 b) {
    vf4 p = a * b;
    return p.x + p.y + p.z + p.w;
}

__device__ __forceinline__ vf4 ld_nt(const vf4* p) {
    return __builtin_nontemporal_load(p);
}

// Row = 75 float4 (1200 B). Lane i covers chunk i; lanes 0..10 also cover
// chunks 64..74 (masked lanes re-read chunk `lane`; contribution zeroed).
__global__ __launch_bounds__(TPB, 4) void sg_main(
    const float* __restrict__ uw, const float* __restrict__ vw,
    const int* __restrict__ pos_u, const int* __restrict__ pos_v,
    const int* __restrict__ neg_v, float* __restrict__ block_sums)
{
    const int lane = threadIdx.x & 63;
    const int wib  = threadIdx.x >> 6;
    int gw = blockIdx.x * (TPB / 64) + wib;
    gw = __builtin_amdgcn_readfirstlane(gw);     // wave-uniform

    const bool c1ok = lane < (75 - 64);          // lanes 0..10
    const int  o2   = c1ok ? (64 + lane) : lane; // in-bounds fallback

    float acc = 0.f;

    #pragma unroll 1
    for (int i = 0; i < B_PER_WAVE; ++i) {
        const int b = gw * B_PER_WAVE + i;       // wave-uniform

        const int iu = pos_u[b];
        const int iv = pos_v[b];
        int nx[K_NEG];
        #pragma unroll
        for (int k = 0; k < K_NEG; ++k) nx[k] = neg_v[b * K_NEG + k];

        const vf4* pr[NROW];
        pr[0] = (const vf4*)(uw + (size_t)iu * DIM);
        pr[1] = (const vf4*)(vw + (size_t)iv * DIM);
        #pragma unroll
        for (int k = 0; k < K_NEG; ++k)
            pr[2 + k] = (const vf4*)(vw + (size_t)nx[k] * DIM);

        // Issue ALL 24 loads before any compute. u-row: non-temporal.
        vf4 c0[NROW];
        vf4 c1[NROW];
        c0[0] = ld_nt(pr[0] + lane);
        c1[0] = ld_nt(pr[0] + o2);
        #pragma unroll
        for (int j = 1; j < NROW; ++j) c0[j] = pr[j][lane];
        #pragma unroll
        for (int j = 1; j < NROW; ++j) c1[j] = pr[j][o2];

        float part[K_NEG + 1];
        #pragma unroll
        for (int j = 1; j < NROW; ++j) {
            float p = dot4(c0[j], c0[0]);
            float q = dot4(c1[j], c1[0]);
            part[j - 1] = p + (c1ok ? q : 0.f);
        }

        // Butterfly-reduce all 11 dots across the wave (result broadcast).
        #pragma unroll
        for (int s = 1; s < 64; s <<= 1) {
            #pragma unroll
            for (int j = 0; j < K_NEG + 1; ++j)
                part[j] += __shfl_xor(part[j], s, 64);
        }

        // pos: softplus(-score); neg: softplus(+score)
        float score = fminf(fmaxf(part[0], -10.f), 10.f);
        float loss = __logf(1.f + __expf(-score));
        #pragma unroll
        for (int k = 0; k < K_NEG; ++k) {
            float ns = fminf(fmaxf(part[k + 1], -10.f), 10.f);
            loss += __logf(1.f + __expf(ns));
        }
        acc += loss;   // uniform across lanes
    }

    __shared__ float red[TPB / 64];
    if (lane == 0) red[wib] = acc;
    __syncthreads();
    if (threadIdx.x == 0)
        block_sums[blockIdx.x] = red[0] + red[1] + red[2] + red[3];
}

__global__ __launch_bounds__(256) void sg_finalize(
    const float* __restrict__ bs, float* __restrict__ out)
{
    float s = 0.f;
    for (int i = threadIdx.x; i < BLOCKS; i += 256) s += bs[i];
    #pragma unroll
    for (int off = 1; off < 64; off <<= 1) s += __shfl_xor(s, off, 64);
    __shared__ float red[4];
    const int wave = threadIdx.x >> 6;
    if ((threadIdx.x & 63) == 0) red[wave] = s;
    __syncthreads();
    if (threadIdx.x == 0)
        out[0] = (red[0] + red[1] + red[2] + red[3]) * (1.0f / (float)B_TOT);
}

extern "C" void kernel_launch(void* const* d_in, const int* in_sizes, int n_in,
                              void* d_out, int out_size, void* d_ws, size_t ws_size,
                              hipStream_t stream) {
    const float* uw    = (const float*)d_in[0];
    const float* vw    = (const float*)d_in[1];
    const int*   pos_u = (const int*)d_in[2];
    const int*   pos_v = (const int*)d_in[3];
    const int*   neg_v = (const int*)d_in[4];
    float* out = (float*)d_out;
    float* block_sums = (float*)d_ws;

    sg_main<<<BLOCKS, TPB, 0, stream>>>(uw, vw, pos_u, pos_v, neg_v, block_sums);
    sg_finalize<<<1, 256, 0, stream>>>(block_sums, out);
}

// Round 5
// 335.007 us; speedup vs baseline: 1.7881x; 1.0005x over previous
//
#include <hip/hip_runtime.h>
#include <math.h>

// SkipGram negative-sampling loss on MI355X — round 5.
// Single change vs R4: finer-grained blocks (4096 blocks x 4 b/wave instead
// of 2048 x 8) to enable backfill and shrink the completion tail.
// Discriminating test: fabric-roofline model says NEUTRAL; occupancy/tail
// model says -15..-20%.

#define DIM   300
#define B_TOT 65536
#define K_NEG 10
#define NROW  (K_NEG + 2)   // u, pos_v, 10 negs

constexpr int BLOCKS = 4096;
constexpr int TPB    = 256;
constexpr int WAVES  = BLOCKS * (TPB / 64);   // 16384
constexpr int B_PER_WAVE = B_TOT / WAVES;     // 4

typedef float vf4 __attribute__((ext_vector_type(4)));

__device__ __forceinline__ float dot4(vf4 a, vf4 b) {
    vf4 p = a * b;
    return p.x + p.y + p.z + p.w;
}

__device__ __forceinline__ vf4 ld_nt(const vf4* p) {
    return __builtin_nontemporal_load(p);
}

// Row = 75 float4 (1200 B). Lane i covers chunk i; lanes 0..10 also cover
// chunks 64..74 (masked lanes re-read chunk `lane`; contribution zeroed —
// same line as the c0 load -> L1 hit, no extra fabric traffic).
__global__ __launch_bounds__(TPB, 4) void sg_main(
    const float* __restrict__ uw, const float* __restrict__ vw,
    const int* __restrict__ pos_u, const int* __restrict__ pos_v,
    const int* __restrict__ neg_v, float* __restrict__ block_sums)
{
    const int lane = threadIdx.x & 63;
    const int wib  = threadIdx.x >> 6;
    int gw = blockIdx.x * (TPB / 64) + wib;
    gw = __builtin_amdgcn_readfirstlane(gw);     // wave-uniform

    const bool c1ok = lane < (75 - 64);          // lanes 0..10
    const int  o2   = c1ok ? (64 + lane) : lane; // in-bounds fallback

    float acc = 0.f;

    #pragma unroll 1
    for (int i = 0; i < B_PER_WAVE; ++i) {
        const int b = gw * B_PER_WAVE + i;       // wave-uniform

        const int iu = pos_u[b];
        const int iv = pos_v[b];
        int nx[K_NEG];
        #pragma unroll
        for (int k = 0; k < K_NEG; ++k) nx[k] = neg_v[b * K_NEG + k];

        const vf4* pr[NROW];
        pr[0] = (const vf4*)(uw + (size_t)iu * DIM);
        pr[1] = (const vf4*)(vw + (size_t)iv * DIM);
        #pragma unroll
        for (int k = 0; k < K_NEG; ++k)
            pr[2 + k] = (const vf4*)(vw + (size_t)nx[k] * DIM);

        // Issue loads before compute. u-row: non-temporal (low reuse).
        vf4 c0[NROW];
        vf4 c1[NROW];
        c0[0] = ld_nt(pr[0] + lane);
        c1[0] = ld_nt(pr[0] + o2);
        #pragma unroll
        for (int j = 1; j < NROW; ++j) c0[j] = pr[j][lane];
        #pragma unroll
        for (int j = 1; j < NROW; ++j) c1[j] = pr[j][o2];

        float part[K_NEG + 1];
        #pragma unroll
        for (int j = 1; j < NROW; ++j) {
            float p = dot4(c0[j], c0[0]);
            float q = dot4(c1[j], c1[0]);
            part[j - 1] = p + (c1ok ? q : 0.f);
        }

        // Butterfly-reduce all 11 dots across the wave (result broadcast).
        #pragma unroll
        for (int s = 1; s < 64; s <<= 1) {
            #pragma unroll
            for (int j = 0; j < K_NEG + 1; ++j)
                part[j] += __shfl_xor(part[j], s, 64);
        }

        // pos: softplus(-score); neg: softplus(+score)
        float score = fminf(fmaxf(part[0], -10.f), 10.f);
        float loss = __logf(1.f + __expf(-score));
        #pragma unroll
        for (int k = 0; k < K_NEG; ++k) {
            float ns = fminf(fmaxf(part[k + 1], -10.f), 10.f);
            loss += __logf(1.f + __expf(ns));
        }
        acc += loss;   // uniform across lanes
    }

    __shared__ float red[TPB / 64];
    if (lane == 0) red[wib] = acc;
    __syncthreads();
    if (threadIdx.x == 0)
        block_sums[blockIdx.x] = red[0] + red[1] + red[2] + red[3];
}

__global__ __launch_bounds__(256) void sg_finalize(
    const float* __restrict__ bs, float* __restrict__ out)
{
    float s = 0.f;
    for (int i = threadIdx.x; i < BLOCKS; i += 256) s += bs[i];
    #pragma unroll
    for (int off = 1; off < 64; off <<= 1) s += __shfl_xor(s, off, 64);
    __shared__ float red[4];
    const int wave = threadIdx.x >> 6;
    if ((threadIdx.x & 63) == 0) red[wave] = s;
    __syncthreads();
    if (threadIdx.x == 0)
        out[0] = (red[0] + red[1] + red[2] + red[3]) * (1.0f / (float)B_TOT);
}

extern "C" void kernel_launch(void* const* d_in, const int* in_sizes, int n_in,
                              void* d_out, int out_size, void* d_ws, size_t ws_size,
                              hipStream_t stream) {
    const float* uw    = (const float*)d_in[0];
    const float* vw    = (const float*)d_in[1];
    const int*   pos_u = (const int*)d_in[2];
    const int*   pos_v = (const int*)d_in[3];
    const int*   neg_v = (const int*)d_in[4];
    float* out = (float*)d_out;
    float* block_sums = (float*)d_ws;

    sg_main<<<BLOCKS, TPB, 0, stream>>>(uw, vw, pos_u, pos_v, neg_v, block_sums);
    sg_finalize<<<1, 256, 0, stream>>>(block_sums, out);
}